// Round 3
// baseline (420.566 us; speedup 1.0000x reference)
//
#include <hip/hip_runtime.h>
#include <math.h>

#define N_B 16
#define C_CH 128
#define T_LEN 513
#define NI 257
#define NJ 256
#define NIB 9                       // ceil(257/32)
#define SCALE (1.4426950408889634f/128.0f)   // log2(e)/C

// workspace (floats)
#define RAM_OFF 0                   // [16][257][256] = 1,052,672
#define PDA_OFF 1052672             // [16][9][256]   = 36,864

typedef float v2f __attribute__((ext_vector_type(2)));
typedef const __attribute__((address_space(1))) void GVOID;
typedef __attribute__((address_space(3))) void LVOID;

// ---- K1: S[i,j] = sum_c (x1[c,i]-x2[c,j])^2 ; RAM = exp2(S*log2e/128);
//      writes RAM + per-(i-block) partial column sums. 1 wave/block, 32x64 tile.
__global__ __launch_bounds__(64) void k_gemm(const float* __restrict__ x,
                                             float* __restrict__ ram,
                                             float* __restrict__ pda) {
    const int n = blockIdx.z, ib = blockIdx.y, jb = blockIdx.x;
    const int i0 = ib * 32, j0 = jb * 64;
    __shared__ float s1[2][512];     // [buf][cc*32+e]  e: i-offset
    __shared__ float s2[2][1024];    // [buf][cc*64+e]  e: j-offset
    const int lane = threadIdx.x;
    const int tx = lane & 15, ty = lane >> 4;
    const float* xn = x + (size_t)n * (C_CH * T_LEN);
    const int e1 = lane & 31;
    const int ccb = lane >> 5;                       // 0/1
    const int ti = min(2 * (i0 + e1), 512);          // clamped for i>=NI (masked later)
    const int tj = 2 * (j0 + lane) + 1;

    v2f acc[8][2];
    #pragma unroll
    for (int a = 0; a < 8; ++a) { acc[a][0] = (v2f)(0.f); acc[a][1] = (v2f)(0.f); }

    // stage one 16-channel block into buffer buf (flat idx q=64k+lane matches [cc][e])
    #define STAGE(buf, c0) do { \
        _Pragma("unroll") \
        for (int k = 0; k < 8; ++k) { \
            const float* gp = xn + ((c0) + ccb + 2 * k) * T_LEN + ti; \
            __builtin_amdgcn_global_load_lds((GVOID*)gp, (LVOID*)&s1[buf][64 * k], 4, 0, 0); \
        } \
        _Pragma("unroll") \
        for (int k = 0; k < 16; ++k) { \
            const float* gp2 = xn + ((c0) + k) * T_LEN + tj; \
            __builtin_amdgcn_global_load_lds((GVOID*)gp2, (LVOID*)&s2[buf][64 * k], 4, 0, 0); \
        } \
    } while (0)

    #define COMPUTE(buf) do { \
        _Pragma("unroll") \
        for (int cc = 0; cc < 16; ++cc) { \
            float4 a0 = *(const float4*)&s1[buf][cc * 32 + 8 * ty]; \
            float4 a1 = *(const float4*)&s1[buf][cc * 32 + 8 * ty + 4]; \
            float4 b4 = *(const float4*)&s2[buf][cc * 64 + 4 * tx]; \
            v2f b0; b0.x = b4.x; b0.y = b4.y; \
            v2f b1; b1.x = b4.z; b1.y = b4.w; \
            float av[8] = {a0.x, a0.y, a0.z, a0.w, a1.x, a1.y, a1.z, a1.w}; \
            _Pragma("unroll") \
            for (int ii = 0; ii < 8; ++ii) { \
                v2f a2; a2.x = av[ii]; a2.y = av[ii]; \
                v2f d0 = a2 - b0; acc[ii][0] += d0 * d0; \
                v2f d1 = a2 - b1; acc[ii][1] += d1 * d1; \
            } \
        } \
    } while (0)

    STAGE(0, 0);
    asm volatile("s_waitcnt vmcnt(0)" ::: "memory");
    #pragma unroll
    for (int cb = 0; cb < 8; ++cb) {
        if (cb < 7) STAGE((cb + 1) & 1, 16 * (cb + 1));   // prefetch next (in flight)
        COMPUTE(cb & 1);
        asm volatile("s_waitcnt vmcnt(0)" ::: "memory");  // next buffer landed
    }

    // epilogue: RAM + partial column sums
    float cs0 = 0.f, cs1 = 0.f, cs2 = 0.f, cs3 = 0.f;
    float* rn = ram + (size_t)n * NI * NJ;
    #pragma unroll
    for (int ii = 0; ii < 8; ++ii) {
        const int i = i0 + 8 * ty + ii;
        float r0 = exp2f(acc[ii][0].x * SCALE);
        float r1 = exp2f(acc[ii][0].y * SCALE);
        float r2 = exp2f(acc[ii][1].x * SCALE);
        float r3 = exp2f(acc[ii][1].y * SCALE);
        if (i < NI) {
            float4 v; v.x = r0; v.y = r1; v.z = r2; v.w = r3;
            *(float4*)&rn[(size_t)i * NJ + j0 + 4 * tx] = v;
            cs0 += r0; cs1 += r1; cs2 += r2; cs3 += r3;
        }
    }
    cs0 += __shfl_xor(cs0, 16, 64); cs0 += __shfl_xor(cs0, 32, 64);
    cs1 += __shfl_xor(cs1, 16, 64); cs1 += __shfl_xor(cs1, 32, 64);
    cs2 += __shfl_xor(cs2, 16, 64); cs2 += __shfl_xor(cs2, 32, 64);
    cs3 += __shfl_xor(cs3, 16, 64); cs3 += __shfl_xor(cs3, 32, 64);
    if (ty == 0) {
        float4 v; v.x = cs0; v.y = cs1; v.z = cs2; v.w = cs3;
        *(float4*)&pda[((size_t)n * NIB + ib) * NJ + j0 + 4 * tx] = v;
    }
    #undef STAGE
    #undef COMPUTE
}

// ---- K2: w_j = rsqrt(da_j); per row: db + rowsum = rsqrt(db)*sum_j RAM*w_j;
//      fused apply: out[n,c,t] = x * 2*rowsum[t>>1] for this block's t-range.
__global__ __launch_bounds__(256) void k_row(const float* __restrict__ ram,
                                             const float* __restrict__ pda,
                                             const float* __restrict__ x,
                                             float* __restrict__ out) {
    const int ic = blockIdx.x, n = blockIdx.y;
    __shared__ float w_s[NJ];
    __shared__ float f_s[16];
    const int tid = threadIdx.x;
    {
        float da = 0.f;
        #pragma unroll
        for (int k = 0; k < NIB; ++k) da += pda[((size_t)n * NIB + k) * NJ + tid];
        w_s[tid] = rsqrtf(da);                   // da >= 257, eps negligible
    }
    __syncthreads();
    const int wv = tid >> 6, lane = tid & 63;
    #pragma unroll
    for (int rr = 0; rr < 4; ++rr) {
        const int lr = wv * 4 + rr;
        const int i = ic * 16 + lr;
        if (i < NI) {
            const float* rrow = ram + ((size_t)n * NI + i) * NJ;
            float db = 0.f, t0 = 0.f;
            #pragma unroll
            for (int k = 0; k < 4; ++k) {
                const float v = rrow[lane + 64 * k];
                db += v;
                t0 = fmaf(v, w_s[lane + 64 * k], t0);
            }
            #pragma unroll
            for (int off = 32; off; off >>= 1) {
                db += __shfl_xor(db, off, 64);
                t0 += __shfl_xor(t0, off, 64);
            }
            if (lane == 0) f_s[lr] = 2.f * t0 * rsqrtf(db);
        }
    }
    __syncthreads();
    // apply for t in [32*ic, 32*ic+32)
    const int tt = tid & 31, cg = tid >> 5;
    const int t = ic * 32 + tt;
    if (t < T_LEN) {
        const float f = f_s[tt >> 1];
        const float* xn = x + (size_t)n * C_CH * T_LEN + t;
        float* on = out + (size_t)n * C_CH * T_LEN + t;
        #pragma unroll
        for (int p = 0; p < 16; ++p) {
            const int c = p * 8 + cg;
            on[c * T_LEN] = xn[c * T_LEN] * f;
        }
    }
}

extern "C" void kernel_launch(void* const* d_in, const int* in_sizes, int n_in,
                              void* d_out, int out_size, void* d_ws, size_t ws_size,
                              hipStream_t stream) {
    const float* x = (const float*)d_in[0];
    float* out = (float*)d_out;
    float* ws = (float*)d_ws;
    float* ram = ws + RAM_OFF;
    float* pda = ws + PDA_OFF;

    k_gemm<<<dim3(NJ / 64, NIB, N_B), 64, 0, stream>>>(x, ram, pda);
    k_row<<<dim3(17, N_B), 256, 0, stream>>>(ram, pda, x, out);
}

// Round 4
// 37.205 us; speedup vs baseline: 11.3041x; 11.3041x over previous
//
#include <hip/hip_runtime.h>
#include <math.h>

#define N_B 16
#define C_CH 128
#define T_LEN 513
#define NI 257
#define NJ 256
#define NIB 17                                 // 17 i-tiles of 16 rows (272)
#define SCALE (1.4426950408889634f/128.0f)     // log2(e)/C

// float offsets in workspace
#define RAM_OFF 0                              // f32 [16][257][256]
#define PDA_OFF (RAM_OFF + N_B*NI*NJ)          // f32 [16][17][256]
#define P_OFF   (PDA_OFF + N_B*NIB*NJ)         // f32 [16][288]
#define Q_OFF   (P_OFF + N_B*288)              // f32 [16][256]
#define AH_OFF  (Q_OFF + N_B*256)              // u16 [16][288][128]
#define AL_OFF  (AH_OFF + N_B*288*64)
#define BH_OFF  (AL_OFF + N_B*288*64)          // u16 [16][256][128]
#define BL_OFF  (BH_OFF + N_B*256*64)
// total ~9 MB

typedef unsigned short u16;
typedef u16 u16x8 __attribute__((ext_vector_type(8)));
typedef short bf16x8 __attribute__((ext_vector_type(8)));
typedef float f32x4 __attribute__((ext_vector_type(4)));

__device__ inline u16 bf16_rne(float f) {
    unsigned u = __builtin_bit_cast(unsigned, f);
    return (u16)((u + 0x7fffu + ((u >> 16) & 1u)) >> 16);
}

// ---- K0: transpose x -> t-major bf16 hi/lo planes; exact fp32 P_i = sum x1^2, Q_j = sum x2^2.
//      Pads A rows [257,288) and P entries with zeros (tb=8 block covers t in [512,576)).
__global__ __launch_bounds__(256) void k_prep(const float* __restrict__ x,
        u16* __restrict__ Ah, u16* __restrict__ Al,
        u16* __restrict__ Bh, u16* __restrict__ Bl,
        float* __restrict__ P, float* __restrict__ Q) {
    const int tb = blockIdx.x, n = blockIdx.y;
    const int t0 = tb * 64;
    __shared__ float s[64][129];
    const int tid = threadIdx.x;
    {
        const int tt = tid & 63, w = tid >> 6;
        const float* xn = x + (size_t)n * C_CH * T_LEN;
        const int t = t0 + tt;
        #pragma unroll
        for (int k = 0; k < 32; ++k) {
            const int c = w + 4 * k;
            s[tt][c] = (t < T_LEN) ? xn[c * T_LEN + t] : 0.f;   // zero-pad invalid t
        }
    }
    __syncthreads();
    const int r = tid >> 2, cq = (tid & 3) * 32;
    const int t = t0 + r;
    const int row = t >> 1;                       // <= 287
    const bool isA = (t & 1) == 0;
    u16* hp; u16* lp; bool dowrite;
    if (isA) {
        hp = Ah + ((size_t)n * 288 + row) * 128 + cq;
        lp = Al + ((size_t)n * 288 + row) * 128 + cq;
        dowrite = true;                           // includes zero pad rows
    } else {
        hp = Bh + ((size_t)n * 256 + row) * 128 + cq;
        lp = Bl + ((size_t)n * 256 + row) * 128 + cq;
        dowrite = (row < 256);
    }
    float fsq = 0.f;
    #pragma unroll
    for (int q = 0; q < 4; ++q) {
        u16x8 hv, lv;
        #pragma unroll
        for (int e = 0; e < 8; ++e) {
            const float f = s[r][cq + 8 * q + e];
            const u16 hb = bf16_rne(f);
            const float hf = __builtin_bit_cast(float, (unsigned)hb << 16);
            hv[e] = hb;
            lv[e] = bf16_rne(f - hf);
            fsq = fmaf(f, f, fsq);
        }
        if (dowrite) { *(u16x8*)(hp + 8 * q) = hv; *(u16x8*)(lp + 8 * q) = lv; }
    }
    fsq += __shfl_xor(fsq, 1, 64);
    fsq += __shfl_xor(fsq, 2, 64);
    if ((tid & 3) == 0) {
        if (isA) P[n * 288 + row] = fsq;          // zero for pad rows
        else if (row < 256) Q[n * 256 + row] = fsq;
    }
}

// ---- K1: one 16x16 output tile per wave. cross = hi*hi + hi*lo + lo*hi (12 MFMAs);
//      S = P + Q - 2*cross; RAM = exp2(S*sc); fused RAM store + pda column partials.
__global__ __launch_bounds__(128) void k_mfma(const u16* __restrict__ Ah, const u16* __restrict__ Al,
        const u16* __restrict__ Bh, const u16* __restrict__ Bl,
        const float* __restrict__ P, const float* __restrict__ Q,
        float* __restrict__ ram, float* __restrict__ pda) {
    const int wv = blockIdx.x * 2 + (threadIdx.x >> 6);   // 0..4351
    const int l = threadIdx.x & 63;
    const int n = wv / 272, rem = wv % 272;
    const int ib = rem >> 4, jb = rem & 15;
    const int i0 = ib * 16, j0 = jb * 16;
    const int il = l & 15, g = l >> 4;
    const size_t abase = ((size_t)n * 288 + i0 + il) * 128 + 8 * g;
    const size_t bbase = ((size_t)n * 256 + j0 + il) * 128 + 8 * g;
    f32x4 acc = {0.f, 0.f, 0.f, 0.f};
    #pragma unroll
    for (int kc = 0; kc < 4; ++kc) {
        bf16x8 ah = *(const bf16x8*)(Ah + abase + 32 * kc);
        bf16x8 al = *(const bf16x8*)(Al + abase + 32 * kc);
        bf16x8 bh = *(const bf16x8*)(Bh + bbase + 32 * kc);
        bf16x8 bl = *(const bf16x8*)(Bl + bbase + 32 * kc);
        acc = __builtin_amdgcn_mfma_f32_16x16x32_bf16(ah, bh, acc, 0, 0, 0);
        acc = __builtin_amdgcn_mfma_f32_16x16x32_bf16(ah, bl, acc, 0, 0, 0);
        acc = __builtin_amdgcn_mfma_f32_16x16x32_bf16(al, bh, acc, 0, 0, 0);
    }
    const float4 p4 = *(const float4*)&P[n * 288 + i0 + 4 * g];
    const float qv = Q[n * 256 + j0 + il];
    const float pv[4] = {p4.x, p4.y, p4.z, p4.w};
    float cs = 0.f;
    float* rn = ram + (size_t)n * NI * NJ;
    #pragma unroll
    for (int r = 0; r < 4; ++r) {
        const int i = i0 + 4 * g + r;
        const float Sv = pv[r] + qv - 2.f * acc[r];
        const float rv = exp2f(Sv * SCALE);       // RAM >= 1 => 0.5-threshold is dead code
        if (i < NI) { rn[(size_t)i * NJ + j0 + il] = rv; cs += rv; }
    }
    cs += __shfl_xor(cs, 16, 64);
    cs += __shfl_xor(cs, 32, 64);
    if (l < 16) pda[((size_t)n * NIB + ib) * NJ + j0 + il] = cs;
}

// ---- K2: w_j = rsqrt(da_j); per row db + rowsum = rsqrt(db)*sum_j RAM*w_j; fused apply.
__global__ __launch_bounds__(256) void k_row(const float* __restrict__ ram,
        const float* __restrict__ pda, const float* __restrict__ x,
        float* __restrict__ out) {
    const int ic = blockIdx.x, n = blockIdx.y;
    __shared__ float w_s[NJ];
    __shared__ float f_s[16];
    const int tid = threadIdx.x;
    {
        float da = 0.f;
        #pragma unroll
        for (int k = 0; k < NIB; ++k) da += pda[((size_t)n * NIB + k) * NJ + tid];
        w_s[tid] = rsqrtf(da);                    // da >= 257, eps negligible
    }
    __syncthreads();
    const int wv = tid >> 6, lane = tid & 63;
    #pragma unroll
    for (int rr = 0; rr < 4; ++rr) {
        const int lr = wv * 4 + rr;
        const int i = ic * 16 + lr;
        if (i < NI) {
            const float* rrow = ram + ((size_t)n * NI + i) * NJ;
            float db = 0.f, t0 = 0.f;
            #pragma unroll
            for (int k = 0; k < 4; ++k) {
                const float v = rrow[lane + 64 * k];
                db += v;
                t0 = fmaf(v, w_s[lane + 64 * k], t0);
            }
            #pragma unroll
            for (int off = 32; off; off >>= 1) {
                db += __shfl_xor(db, off, 64);
                t0 += __shfl_xor(t0, off, 64);
            }
            if (lane == 0) f_s[lr] = 2.f * t0 * rsqrtf(db);
        }
    }
    __syncthreads();
    const int tt = tid & 31, cg = tid >> 5;
    const int t = ic * 32 + tt;
    if (t < T_LEN) {
        const float f = f_s[tt >> 1];
        const float* xn = x + (size_t)n * C_CH * T_LEN + t;
        float* on = out + (size_t)n * C_CH * T_LEN + t;
        #pragma unroll
        for (int p = 0; p < 16; ++p) {
            const int c = p * 8 + cg;
            on[c * T_LEN] = xn[c * T_LEN] * f;
        }
    }
}

extern "C" void kernel_launch(void* const* d_in, const int* in_sizes, int n_in,
                              void* d_out, int out_size, void* d_ws, size_t ws_size,
                              hipStream_t stream) {
    const float* x = (const float*)d_in[0];
    float* out = (float*)d_out;
    float* ws = (float*)d_ws;
    float* ram = ws + RAM_OFF;
    float* pda = ws + PDA_OFF;
    float* P   = ws + P_OFF;
    float* Q   = ws + Q_OFF;
    u16* Ah = (u16*)(ws + AH_OFF);
    u16* Al = (u16*)(ws + AL_OFF);
    u16* Bh = (u16*)(ws + BH_OFF);
    u16* Bl = (u16*)(ws + BL_OFF);

    k_prep<<<dim3(9, N_B), 256, 0, stream>>>(x, Ah, Al, Bh, Bl, P, Q);
    k_mfma<<<2176, 128, 0, stream>>>(Ah, Al, Bh, Bl, P, Q, ram, pda);
    k_row<<<dim3(NIB, N_B), 256, 0, stream>>>(ram, pda, x, out);
}